// Round 2
// baseline (2313.575 us; speedup 1.0000x reference)
//
#include <hip/hip_runtime.h>
#include <cstddef>
#include <cstdint>

#define Lc 33
#define Dc 2048
#define DBc 1024
#define Pc 24
#define Bc 2048

typedef __attribute__((ext_vector_type(4))) float f32x4;
typedef __attribute__((ext_vector_type(8))) short s16x8;
typedef __attribute__((ext_vector_type(4))) short s16x4;

__device__ __forceinline__ short bf16r(float f) {
  unsigned u = __float_as_uint(f);
  u = (u + 0x7fffu + ((u >> 16) & 1u)) >> 16;
  return (short)u;
}
__device__ __forceinline__ float bf2f(short s) {
  return __uint_as_float(((unsigned)(unsigned short)s) << 16);
}
__device__ __forceinline__ s16x8 pack8(const float* f) {
  s16x8 r;
#pragma unroll
  for (int i = 0; i < 8; ++i) r[i] = bf16r(f[i]);
  return r;
}
__device__ __forceinline__ void split8(const float* f, s16x8& hi, s16x8& lo) {
#pragma unroll
  for (int i = 0; i < 8; ++i) {
    short h = bf16r(f[i]);
    hi[i] = h;
    lo[i] = bf16r(f[i] - bf2f(h));
  }
}

// ---------------------------------------------------------------------------
// keys = pos_emb @ Wk   (33 x 2048, K=24)  -- tiny, f32 exact
// ---------------------------------------------------------------------------
__global__ __launch_bounds__(256)
void keys_kernel(const float* __restrict__ pe, const float* __restrict__ Wk,
                 float* __restrict__ keys) {
  const int l = blockIdx.x;
  const int d = blockIdx.y * 256 + threadIdx.x;
  float s = 0.f;
#pragma unroll
  for (int p = 0; p < Pc; ++p) s += pe[l * Pc + p] * Wk[(size_t)p * Dc + d];
  keys[(size_t)l * Dc + d] = s;
}

// ---------------------------------------------------------------------------
// Fused batched GEMM, 128x128 tile, BK=32, 4 waves, mfma_f32_16x16x32_bf16.
// MODE 1, SPLITQ 0: h[b,z,:] = gelu(x[:,z,:] @ W1[z] + b1[z])  -> bf16
// MODE 1, SPLITQ 1: hq = gelu(z_L @ Wq1 + bq1)                 -> f32 (split-bf16, 3 MFMA)
// MODE 2, SPLITQ 0: values[b,z,:] = h_ln @ W2[z] + b2[z]       -> bf16
// MODE 2, SPLITQ 1: query = 1+elu(z_L + hq_ln @ Wq2 + bq2)     -> f32 (split-bf16)
// ---------------------------------------------------------------------------
template <int MODE, int SPLITQ>
__global__ __launch_bounds__(256, 2)
void gemm_fused(const float* __restrict__ x,
                const unsigned short* __restrict__ hbuf,
                const float* __restrict__ hqF,
                const float* __restrict__ Wmain, const float* __restrict__ Wq,
                const float* __restrict__ bmain, const float* __restrict__ bq,
                unsigned short* __restrict__ outH, float* __restrict__ outHq,
                unsigned short* __restrict__ outV, float* __restrict__ outQ) {
  constexpr int K = (MODE == 1) ? 2048 : 1024;
  constexpr int N = (MODE == 1) ? 1024 : 2048;
  constexpr int BK = 32;
  constexpr int NT = K / BK;

  const int z = blockIdx.z;
  const int bm = blockIdx.x;
  const int bn = blockIdx.y;
  const int tid = threadIdx.x;
  const int lane = tid & 63;
  const int wid = tid >> 6;
  const int wr = (wid >> 1) * 64;
  const int wc = (wid & 1) * 64;
  const int l15 = lane & 15;
  const int kb = lane >> 4;

  const float* Bp = SPLITQ ? Wq : (Wmain + (size_t)z * K * N);

  __shared__ short Als[1 + SPLITQ][128][32];
  __shared__ short Bls[1 + SPLITQ][128][32];

  const f32x4 vzero = {0.f, 0.f, 0.f, 0.f};
  f32x4 acc[4][4];
#pragma unroll
  for (int m = 0; m < 4; ++m)
#pragma unroll
    for (int n = 0; n < 4; ++n) acc[m][n] = vzero;

  // A staging: thread -> (row = tid>>1, k-halfrange = (tid&1)*16)
  const int ar = tid >> 1;
  const int ak = (tid & 1) * 16;
  const int grow = bm * 128 + ar;

  const float* ApF = nullptr;
  const unsigned short* ApH = nullptr;
  if constexpr (MODE == 1) {
    const int lsel = SPLITQ ? (Lc - 1) : z;
    ApF = x + (size_t)grow * (Lc * Dc) + (size_t)lsel * Dc + ak;
  } else if constexpr (SPLITQ == 1) {
    ApF = hqF + (size_t)grow * DBc + ak;
  } else {
    ApH = hbuf + ((size_t)grow * 33 + z) * DBc + ak;
  }

  // B staging: thread -> (col n = tid&127, two k-chunks of 8, bank-balanced)
  const int bnL = tid & 127;
  const int bj = tid >> 7;
  const int c0 = ((bnL >> 1) & 3) ^ bj;
  const int kc0 = c0 * 8;
  const int kc1 = (c0 ^ 2) * 8;
  const float* Bcol = Bp + (size_t)bn * 128 + bnL;

  float aF[16];
  s16x8 aH0, aH1;
  float bF[16];

  auto loadA = [&](int kt) {
    if constexpr (MODE == 2 && SPLITQ == 0) {
      const unsigned short* p = ApH + kt * BK;
      aH0 = *(const s16x8*)p;
      aH1 = *(const s16x8*)(p + 8);
    } else {
      const float* p = ApF + kt * BK;
#pragma unroll
      for (int i = 0; i < 4; ++i) {
        f32x4 t = *(const f32x4*)(p + i * 4);
#pragma unroll
        for (int j = 0; j < 4; ++j) aF[i * 4 + j] = t[j];
      }
    }
  };
  auto loadB = [&](int kt) {
    const float* p0 = Bcol + (size_t)(kt * BK + kc0) * N;
    const float* p1 = Bcol + (size_t)(kt * BK + kc1) * N;
#pragma unroll
    for (int i = 0; i < 8; ++i) bF[i] = p0[(size_t)i * N];
#pragma unroll
    for (int i = 0; i < 8; ++i) bF[8 + i] = p1[(size_t)i * N];
  };
  auto writeLDS = [&]() {
    if constexpr (MODE == 2 && SPLITQ == 0) {
      *(s16x8*)&Als[0][ar][ak] = aH0;
      *(s16x8*)&Als[0][ar][ak + 8] = aH1;
    } else if constexpr (SPLITQ == 0) {
      *(s16x8*)&Als[0][ar][ak] = pack8(aF);
      *(s16x8*)&Als[0][ar][ak + 8] = pack8(aF + 8);
    } else {
      s16x8 h0, l0, h1, l1;
      split8(aF, h0, l0);
      split8(aF + 8, h1, l1);
      *(s16x8*)&Als[0][ar][ak] = h0;
      *(s16x8*)&Als[1][ar][ak] = l0;
      *(s16x8*)&Als[0][ar][ak + 8] = h1;
      *(s16x8*)&Als[1][ar][ak + 8] = l1;
    }
    if constexpr (SPLITQ == 0) {
      *(s16x8*)&Bls[0][bnL][kc0] = pack8(bF);
      *(s16x8*)&Bls[0][bnL][kc1] = pack8(bF + 8);
    } else {
      s16x8 h0, l0, h1, l1;
      split8(bF, h0, l0);
      split8(bF + 8, h1, l1);
      *(s16x8*)&Bls[0][bnL][kc0] = h0;
      *(s16x8*)&Bls[1][bnL][kc0] = l0;
      *(s16x8*)&Bls[0][bnL][kc1] = h1;
      *(s16x8*)&Bls[1][bnL][kc1] = l1;
    }
  };

  loadA(0);
  loadB(0);
  for (int kt = 0; kt < NT; ++kt) {
    __syncthreads();
    writeLDS();
    if (kt + 1 < NT) {
      loadA(kt + 1);
      loadB(kt + 1);
    }
    __syncthreads();
    s16x8 af[4], bfv[4];
#pragma unroll
    for (int m = 0; m < 4; ++m)
      af[m] = *(const s16x8*)&Als[0][wr + m * 16 + l15][kb * 8];
#pragma unroll
    for (int n = 0; n < 4; ++n)
      bfv[n] = *(const s16x8*)&Bls[0][wc + n * 16 + l15][kb * 8];
    if constexpr (SPLITQ == 1) {
      s16x8 afl[4], bfl[4];
#pragma unroll
      for (int m = 0; m < 4; ++m)
        afl[m] = *(const s16x8*)&Als[1][wr + m * 16 + l15][kb * 8];
#pragma unroll
      for (int n = 0; n < 4; ++n)
        bfl[n] = *(const s16x8*)&Bls[1][wc + n * 16 + l15][kb * 8];
#pragma unroll
      for (int m = 0; m < 4; ++m)
#pragma unroll
        for (int n = 0; n < 4; ++n) {
          acc[m][n] = __builtin_amdgcn_mfma_f32_16x16x32_bf16(
              af[m], bfv[n], acc[m][n], 0, 0, 0);
          acc[m][n] = __builtin_amdgcn_mfma_f32_16x16x32_bf16(
              af[m], bfl[n], acc[m][n], 0, 0, 0);
          acc[m][n] = __builtin_amdgcn_mfma_f32_16x16x32_bf16(
              afl[m], bfv[n], acc[m][n], 0, 0, 0);
        }
    } else {
#pragma unroll
      for (int m = 0; m < 4; ++m)
#pragma unroll
        for (int n = 0; n < 4; ++n)
          acc[m][n] = __builtin_amdgcn_mfma_f32_16x16x32_bf16(
              af[m], bfv[n], acc[m][n], 0, 0, 0);
    }
  }

  const float* biasP = SPLITQ ? bq : (bmain + (size_t)z * N);
#pragma unroll
  for (int m = 0; m < 4; ++m) {
    const int r0 = bm * 128 + wr + m * 16 + kb * 4;
#pragma unroll
    for (int n = 0; n < 4; ++n) {
      const int col = bn * 128 + wc + n * 16 + l15;
      const float bs = biasP[col];
#pragma unroll
      for (int j = 0; j < 4; ++j) {
        const int r = r0 + j;
        const float v = acc[m][n][j] + bs;
        if constexpr (MODE == 1 && SPLITQ == 0) {
          const float g = 0.5f * v * (1.0f + erff(v * 0.70710678118f));
          outH[((size_t)r * 33 + z) * DBc + col] = (unsigned short)bf16r(g);
        } else if constexpr (MODE == 1 && SPLITQ == 1) {
          const float g = 0.5f * v * (1.0f + erff(v * 0.70710678118f));
          outHq[(size_t)r * DBc + col] = g;
        } else if constexpr (MODE == 2 && SPLITQ == 0) {
          outV[((size_t)r * 33 + z) * Dc + col] = (unsigned short)bf16r(v);
        } else {
          const float zl =
              x[(size_t)r * (Lc * Dc) + (size_t)(Lc - 1) * Dc + col];
          const float t = zl + v;
          outQ[(size_t)r * Dc + col] = (t > 0.f) ? (1.f + t) : __expf(t);
        }
      }
    }
  }
}

// ---------------------------------------------------------------------------
// Row LayerNorm over last dim W, in place on bf16 buffer. 33 slots.
// ---------------------------------------------------------------------------
template <int W>
__global__ __launch_bounds__(256)
void ln_kernel(unsigned short* __restrict__ buf, const float* __restrict__ gmain,
               const float* __restrict__ bmain) {
  constexpr int E = W / 256;
  const int z = blockIdx.x;
  const int b = blockIdx.y;
  const int tid = threadIdx.x;
  unsigned short* row = buf + ((size_t)b * 33 + z) * W;
  float v[E];
  if constexpr (E == 4) {
    s16x4 t = *(const s16x4*)(row + tid * 4);
#pragma unroll
    for (int i = 0; i < 4; ++i) v[i] = bf2f(t[i]);
  } else {
    s16x8 t = *(const s16x8*)(row + tid * 8);
#pragma unroll
    for (int i = 0; i < 8; ++i) v[i] = bf2f(t[i]);
  }
  float s = 0.f, s2 = 0.f;
#pragma unroll
  for (int i = 0; i < E; ++i) {
    s += v[i];
    s2 += v[i] * v[i];
  }
#pragma unroll
  for (int o = 32; o > 0; o >>= 1) {
    s += __shfl_xor(s, o);
    s2 += __shfl_xor(s2, o);
  }
  __shared__ float red[2][4];
  const int w = tid >> 6;
  if ((tid & 63) == 0) {
    red[0][w] = s;
    red[1][w] = s2;
  }
  __syncthreads();
  s = red[0][0] + red[0][1] + red[0][2] + red[0][3];
  s2 = red[1][0] + red[1][1] + red[1][2] + red[1][3];
  const float mu = s * (1.0f / W);
  const float var = s2 * (1.0f / W) - mu * mu;
  const float rstd = rsqrtf(var + 1e-5f);
  const float* G = gmain + (size_t)z * W;
  const float* Bt = bmain + (size_t)z * W;
  if constexpr (E == 4) {
    f32x4 gv = *(const f32x4*)(G + tid * 4);
    f32x4 bv = *(const f32x4*)(Bt + tid * 4);
    s16x4 o;
#pragma unroll
    for (int i = 0; i < 4; ++i)
      o[i] = bf16r((v[i] - mu) * rstd * gv[i] + bv[i]);
    *(s16x4*)(row + tid * 4) = o;
  } else {
    f32x4 g0 = *(const f32x4*)(G + tid * 8);
    f32x4 g1 = *(const f32x4*)(G + tid * 8 + 4);
    f32x4 b0 = *(const f32x4*)(Bt + tid * 8);
    f32x4 b1 = *(const f32x4*)(Bt + tid * 8 + 4);
    s16x8 o;
#pragma unroll
    for (int i = 0; i < 4; ++i) {
      o[i] = bf16r((v[i] - mu) * rstd * g0[i] + b0[i]);
      o[i + 4] = bf16r((v[i + 4] - mu) * rstd * g1[i] + b1[i]);
    }
    *(s16x8*)(row + tid * 8) = o;
  }
}

// ---------------------------------------------------------------------------
// f32 LayerNorm for hq (2048 rows x 1024), in place.
// ---------------------------------------------------------------------------
__global__ __launch_bounds__(256)
void ln_f32_kernel(float* __restrict__ buf, const float* __restrict__ g,
                   const float* __restrict__ bb) {
  const int r = blockIdx.x;
  const int tid = threadIdx.x;
  float* row = buf + (size_t)r * DBc;
  f32x4 v = *(const f32x4*)(row + tid * 4);
  float s = 0.f, s2 = 0.f;
#pragma unroll
  for (int i = 0; i < 4; ++i) {
    s += v[i];
    s2 += v[i] * v[i];
  }
#pragma unroll
  for (int o = 32; o > 0; o >>= 1) {
    s += __shfl_xor(s, o);
    s2 += __shfl_xor(s2, o);
  }
  __shared__ float red[2][4];
  const int w = tid >> 6;
  if ((tid & 63) == 0) {
    red[0][w] = s;
    red[1][w] = s2;
  }
  __syncthreads();
  s = red[0][0] + red[0][1] + red[0][2] + red[0][3];
  s2 = red[1][0] + red[1][1] + red[1][2] + red[1][3];
  const float mu = s * (1.0f / DBc);
  const float var = s2 * (1.0f / DBc) - mu * mu;
  const float rstd = rsqrtf(var + 1e-5f);
  f32x4 gv = *(const f32x4*)(g + tid * 4);
  f32x4 bv = *(const f32x4*)(bb + tid * 4);
  f32x4 o;
#pragma unroll
  for (int i = 0; i < 4; ++i) o[i] = (v[i] - mu) * rstd * gv[i] + bv[i];
  *(f32x4*)(row + tid * 4) = o;
}

// ---------------------------------------------------------------------------
// Final attention: per-b block. logits(33) -> softmax -> weighted values sum.
// ---------------------------------------------------------------------------
__global__ __launch_bounds__(256)
void attn_kernel(const float* __restrict__ x, const float* __restrict__ query,
                 const float* __restrict__ keys,
                 const unsigned short* __restrict__ vals,
                 float* __restrict__ out) {
  const int b = blockIdx.x;
  const int tid = threadIdx.x;
  const int d0 = tid * 8;

  float q[8];
  {
    f32x4 t0 = *(const f32x4*)(query + (size_t)b * Dc + d0);
    f32x4 t1 = *(const f32x4*)(query + (size_t)b * Dc + d0 + 4);
#pragma unroll
    for (int i = 0; i < 4; ++i) {
      q[i] = t0[i];
      q[i + 4] = t1[i];
    }
  }
  float s[33];
#pragma unroll
  for (int l = 0; l < 33; ++l) {
    const float* kp = keys + (size_t)l * Dc + d0;
    f32x4 k0 = *(const f32x4*)kp;
    f32x4 k1 = *(const f32x4*)(kp + 4);
    float t = 0.f;
#pragma unroll
    for (int i = 0; i < 4; ++i) t += q[i] * k0[i] + q[i + 4] * k1[i];
    s[l] = t;
  }
#pragma unroll
  for (int l = 0; l < 33; ++l) {
    float v = s[l];
#pragma unroll
    for (int o = 32; o > 0; o >>= 1) v += __shfl_xor(v, o);
    s[l] = v;
  }
  __shared__ float sred[4][33];
  __shared__ float sl[33];
  const int w = tid >> 6;
  if ((tid & 63) == 0) {
#pragma unroll
    for (int l = 0; l < 33; ++l) sred[w][l] = s[l];
  }
  __syncthreads();
  if (tid < 33)
    sl[tid] = sred[0][tid] + sred[1][tid] + sred[2][tid] + sred[3][tid];
  __syncthreads();

  float m = -1e30f;
#pragma unroll
  for (int l = 0; l < 33; ++l) m = fmaxf(m, sl[l]);
  float p[33];
  float sum = 0.f;
#pragma unroll
  for (int l = 0; l < 33; ++l) {
    p[l] = __expf(sl[l] - m);
    sum += p[l];
  }
  const float inv = 1.0f / sum;

  float acc8[8];
  {
    const float* zl = x + (size_t)b * (Lc * Dc) + (size_t)(Lc - 1) * Dc + d0;
    f32x4 z0 = *(const f32x4*)zl;
    f32x4 z1 = *(const f32x4*)(zl + 4);
#pragma unroll
    for (int i = 0; i < 4; ++i) {
      acc8[i] = z0[i];
      acc8[i + 4] = z1[i];
    }
  }
  const unsigned short* vb = vals + (size_t)b * 33 * Dc + d0;
#pragma unroll
  for (int l = 0; l < 33; ++l) {
    s16x8 vv = *(const s16x8*)(vb + (size_t)l * Dc);
    const float a = p[l] * inv;
#pragma unroll
    for (int i = 0; i < 8; ++i) acc8[i] += a * bf2f(vv[i]);
  }
  f32x4 o0, o1;
#pragma unroll
  for (int i = 0; i < 4; ++i) {
    o0[i] = acc8[i];
    o1[i] = acc8[i + 4];
  }
  *(f32x4*)(out + (size_t)b * Dc + d0) = o0;
  *(f32x4*)(out + (size_t)b * Dc + d0 + 4) = o1;
}

// ---------------------------------------------------------------------------
extern "C" void kernel_launch(void* const* d_in, const int* in_sizes, int n_in,
                              void* d_out, int out_size, void* d_ws,
                              size_t ws_size, hipStream_t stream) {
  const float* x = (const float*)d_in[0];
  const float* pe = (const float*)d_in[1];
  const float* Wk = (const float*)d_in[2];
  const float* W1 = (const float*)d_in[3];
  const float* b1 = (const float*)d_in[4];
  const float* ln1g = (const float*)d_in[5];
  const float* ln1b = (const float*)d_in[6];
  const float* W2 = (const float*)d_in[7];
  const float* b2 = (const float*)d_in[8];
  const float* ln2g = (const float*)d_in[9];
  const float* ln2b = (const float*)d_in[10];
  const float* Wq1 = (const float*)d_in[11];
  const float* bq1 = (const float*)d_in[12];
  const float* lnqg = (const float*)d_in[13];
  const float* lnqb = (const float*)d_in[14];
  const float* Wq2 = (const float*)d_in[15];
  const float* bq2 = (const float*)d_in[16];
  float* out = (float*)d_out;
  char* ws = (char*)d_ws;

  // ws layout (bytes):
  //   keys  f32 [33*2048]        @ 0          (270,336)
  //   query f32 [2048*2048]      @ 270336     (16,777,216)
  //   hq    f32 [2048*1024]      @ 17047552   (8,388,608)
  //   h     bf16 [2048*33*1024]  @ 25436160   (138,412,032)
  //   vals  bf16 [2048*33*2048]  @ 163848192  (276,824,064) -> end 440,672,256
  float* keysP = (float*)(ws);
  float* queryP = (float*)(ws + 270336);
  float* hqP = (float*)(ws + 17047552);
  unsigned short* hP = (unsigned short*)(ws + 25436160);
  unsigned short* valsP = (unsigned short*)(ws + 163848192);

  keys_kernel<<<dim3(33, 8), 256, 0, stream>>>(pe, Wk, keysP);

  gemm_fused<1, 0><<<dim3(16, 8, 33), 256, 0, stream>>>(
      x, nullptr, nullptr, W1, nullptr, b1, nullptr, hP, nullptr, nullptr,
      nullptr);

  gemm_fused<1, 1><<<dim3(16, 8, 1), 256, 0, stream>>>(
      x, nullptr, nullptr, nullptr, Wq1, nullptr, bq1, nullptr, hqP, nullptr,
      nullptr);

  ln_kernel<1024><<<dim3(33, 2048), 256, 0, stream>>>(hP, ln1g, ln1b);

  ln_f32_kernel<<<dim3(2048), 256, 0, stream>>>(hqP, lnqg, lnqb);

  gemm_fused<2, 0><<<dim3(16, 16, 33), 256, 0, stream>>>(
      x, hP, nullptr, W2, nullptr, b2, nullptr, nullptr, nullptr, valsP,
      nullptr);

  gemm_fused<2, 1><<<dim3(16, 16, 1), 256, 0, stream>>>(
      x, nullptr, hqP, nullptr, Wq2, nullptr, bq2, nullptr, nullptr, nullptr,
      queryP);

  ln_kernel<2048><<<dim3(33, 2048), 256, 0, stream>>>(valsP, ln2g, ln2b);

  attn_kernel<<<dim3(2048), 256, 0, stream>>>(x, queryP, keysP, valsP, out);
}

// Round 3
// 1762.640 us; speedup vs baseline: 1.3126x; 1.3126x over previous
//
#include <hip/hip_runtime.h>
#include <cstddef>
#include <cstdint>

#define Lc 33
#define Dc 2048
#define DBc 1024
#define Pc 24
#define Bc 2048

typedef __attribute__((ext_vector_type(4))) float f32x4;
typedef __attribute__((ext_vector_type(8))) short s16x8;
typedef __attribute__((ext_vector_type(4))) short s16x4;

__device__ __forceinline__ short bf16r(float f) {
  unsigned u = __float_as_uint(f);
  u = (u + 0x7fffu + ((u >> 16) & 1u)) >> 16;
  return (short)u;
}
__device__ __forceinline__ float bf2f(short s) {
  return __uint_as_float(((unsigned)(unsigned short)s) << 16);
}
__device__ __forceinline__ s16x8 pack8(const float* f) {
  s16x8 r;
#pragma unroll
  for (int i = 0; i < 8; ++i) r[i] = bf16r(f[i]);
  return r;
}
__device__ __forceinline__ void split8(const float* f, s16x8& hi, s16x8& lo) {
#pragma unroll
  for (int i = 0; i < 8; ++i) {
    short h = bf16r(f[i]);
    hi[i] = h;
    lo[i] = bf16r(f[i] - bf2f(h));
  }
}
__device__ __forceinline__ void gl_lds16(const void* g, void* l) {
  __builtin_amdgcn_global_load_lds(
      (const __attribute__((address_space(1))) unsigned int*)g,
      (__attribute__((address_space(3))) unsigned int*)l, 16, 0, 0);
}

// ---------------------------------------------------------------------------
// keys = pos_emb @ Wk   (33 x 2048, K=24)  -- tiny, f32 exact
// ---------------------------------------------------------------------------
__global__ __launch_bounds__(256)
void keys_kernel(const float* __restrict__ pe, const float* __restrict__ Wk,
                 float* __restrict__ keys) {
  const int l = blockIdx.x;
  const int d = blockIdx.y * 256 + threadIdx.x;
  float s = 0.f;
#pragma unroll
  for (int p = 0; p < Pc; ++p) s += pe[l * Pc + p] * Wk[(size_t)p * Dc + d];
  keys[(size_t)l * Dc + d] = s;
}

// ---------------------------------------------------------------------------
// Transpose + bf16-convert weights: W [z][K][N] f32 -> Wt [z][N][K] bf16.
// 64x64 tiles via LDS.
// ---------------------------------------------------------------------------
template <int K, int N>
__global__ __launch_bounds__(256)
void transpose_w(const float* __restrict__ W, unsigned short* __restrict__ Wt) {
  const int z = blockIdx.z;
  const int k0 = blockIdx.x * 64, n0 = blockIdx.y * 64;
  __shared__ unsigned short tile[64][66];
  const int t = threadIdx.x;
  {
    const int r = t >> 2, cq = (t & 3) * 16;
    const float* src = W + (size_t)z * K * N + (size_t)(k0 + r) * N + n0 + cq;
#pragma unroll
    for (int i = 0; i < 16; i += 4) {
      f32x4 v = *(const f32x4*)(src + i);
#pragma unroll
      for (int j = 0; j < 4; ++j)
        tile[r][cq + i + j] = (unsigned short)bf16r(v[j]);
    }
  }
  __syncthreads();
  {
    const int n = t >> 2, kc = (t & 3) * 16;
    s16x8 o0, o1;
#pragma unroll
    for (int i = 0; i < 8; ++i) {
      o0[i] = tile[kc + i][n];
      o1[i] = tile[kc + 8 + i][n];
    }
    unsigned short* dst =
        Wt + (size_t)z * N * K + (size_t)(n0 + n) * K + k0 + kc;
    *(s16x8*)dst = o0;
    *(s16x8*)(dst + 8) = o1;
  }
}

// ---------------------------------------------------------------------------
// Fast batched GEMM, m97 structure: 128x128 tile, BK=64, 4 waves (2x2),
// global_load_lds staging with pre-swizzled source (T2 XOR swizzle, rule #21),
// swizzled ds_read_b128 fragment reads (conflict-free).
// MODE 1: h[b,z,:] = gelu(x[:,z,:] @ W1t[z]^T + b1[z])  A=f32 reg-staged
// MODE 2: vals[b,z,:] = h_ln @ W2t[z]^T + b2[z]         A=bf16 gload_lds
// ---------------------------------------------------------------------------
template <int MODE>
__global__ __launch_bounds__(256, 2)
void gemm_bf16(const float* __restrict__ xsrc,
               const unsigned short* __restrict__ hsrc,
               const unsigned short* __restrict__ Wt,
               const float* __restrict__ bias,
               unsigned short* __restrict__ outbuf) {
  constexpr int K = (MODE == 1) ? 2048 : 1024;
  constexpr int N = (MODE == 1) ? 1024 : 2048;
  constexpr int NT = K / 64;
  const int z = blockIdx.z, bm = blockIdx.x, bn = blockIdx.y;
  const int tid = threadIdx.x, lane = tid & 63, w = tid >> 6;
  const int wr = (w >> 1) * 64, wc = (w & 1) * 64;
  const int l15 = lane & 15, kb = lane >> 4;

  __shared__ __align__(16) unsigned short Als[128 * 64];
  __shared__ __align__(16) unsigned short Bls[128 * 64];

  f32x4 acc[4][4];
#pragma unroll
  for (int m = 0; m < 4; ++m)
#pragma unroll
    for (int n = 0; n < 4; ++n) {
      acc[m][n][0] = 0.f; acc[m][n][1] = 0.f;
      acc[m][n][2] = 0.f; acc[m][n][3] = 0.f;
    }

  // gload_lds lane mapping: 64 lanes = 8 rows x 8 slots of 16B (128B row)
  const int rl8 = lane >> 3;            // row within call (0..7)
  const int sl = lane & 7;              // 16B slot
  const int swzE = ((sl ^ rl8) << 3);   // swizzled element offset (bf16)

  const unsigned short* Bbase = Wt + (size_t)z * N * K;

  // MODE1 A reg-staging mapping: thread -> (row ar, k-half ahalf*32)
  const int ar = tid >> 1, ahalf = tid & 1;
  const float* ApF = nullptr;
  if constexpr (MODE == 1) {
    ApF = xsrc + (size_t)(bm * 128 + ar) * (Lc * Dc) + (size_t)z * Dc +
          ahalf * 32;
  }

  for (int kt = 0; kt < NT; ++kt) {
    // ---- stage A ----
    f32x4 av[8];
    if constexpr (MODE == 1) {
      const float* p = ApF + kt * 64;
#pragma unroll
      for (int i = 0; i < 8; ++i) av[i] = *(const f32x4*)(p + i * 4);
    } else {
#pragma unroll
      for (int j = 0; j < 4; ++j) {
        const int rloc = w * 32 + j * 8 + rl8;
        const unsigned short* g =
            hsrc + ((size_t)(bm * 128 + rloc) * Lc + z) * DBc + kt * 64 + swzE;
        gl_lds16(g, (char*)Als + w * 4096 + j * 1024);
      }
    }
    // ---- stage B (gload_lds, pre-swizzled source) ----
#pragma unroll
    for (int j = 0; j < 4; ++j) {
      const int rloc = w * 32 + j * 8 + rl8;
      const unsigned short* g =
          Bbase + (size_t)(bn * 128 + rloc) * K + kt * 64 + swzE;
      gl_lds16(g, (char*)Bls + w * 4096 + j * 1024);
    }
    if constexpr (MODE == 1) {
      // convert + swizzled ds_write_b128
#pragma unroll
      for (int c = 0; c < 4; ++c) {
        float f[8];
#pragma unroll
        for (int j = 0; j < 4; ++j) {
          f[j] = av[2 * c][j];
          f[4 + j] = av[2 * c + 1][j];
        }
        s16x8 pk = pack8(f);
        const int s = ahalf * 4 + c;
        *(s16x8*)((char*)Als + ar * 128 + ((s ^ (ar & 7)) << 4)) = pk;
      }
    }
    __syncthreads();
    // ---- compute ----
#pragma unroll
    for (int kk = 0; kk < 2; ++kk) {
      s16x8 af[4], bfv[4];
#pragma unroll
      for (int m = 0; m < 4; ++m) {
        const int row = wr + m * 16 + l15;
        const int slot = kk * 4 + kb;
        af[m] = *(const s16x8*)((const char*)Als + row * 128 +
                                ((slot ^ (row & 7)) << 4));
      }
#pragma unroll
      for (int n = 0; n < 4; ++n) {
        const int row = wc + n * 16 + l15;
        const int slot = kk * 4 + kb;
        bfv[n] = *(const s16x8*)((const char*)Bls + row * 128 +
                                 ((slot ^ (row & 7)) << 4));
      }
#pragma unroll
      for (int m = 0; m < 4; ++m)
#pragma unroll
        for (int n = 0; n < 4; ++n)
          acc[m][n] = __builtin_amdgcn_mfma_f32_16x16x32_bf16(
              af[m], bfv[n], acc[m][n], 0, 0, 0);
    }
    __syncthreads();
  }

  const float* biasP = bias + (size_t)z * N;
#pragma unroll
  for (int m = 0; m < 4; ++m) {
    const int r0 = bm * 128 + wr + m * 16 + kb * 4;
#pragma unroll
    for (int n = 0; n < 4; ++n) {
      const int col = bn * 128 + wc + n * 16 + l15;
      const float bs = biasP[col];
#pragma unroll
      for (int j = 0; j < 4; ++j) {
        const int r = r0 + j;
        const float v = acc[m][n][j] + bs;
        if constexpr (MODE == 1) {
          const float g = 0.5f * v * (1.0f + erff(v * 0.70710678118f));
          outbuf[((size_t)r * Lc + z) * DBc + col] = (unsigned short)bf16r(g);
        } else {
          outbuf[((size_t)r * Lc + z) * Dc + col] = (unsigned short)bf16r(v);
        }
      }
    }
  }
}

// ---------------------------------------------------------------------------
// Old-style fused GEMM (reg-staged, unswizzled). Used for the split-precision
// query path (SPLITQ=1) and as main-path fallback if ws is too small.
// ---------------------------------------------------------------------------
template <int MODE, int SPLITQ>
__global__ __launch_bounds__(256, 2)
void gemm_fused(const float* __restrict__ x,
                const unsigned short* __restrict__ hbuf,
                const float* __restrict__ hqF,
                const float* __restrict__ Wmain, const float* __restrict__ Wq,
                const float* __restrict__ bmain, const float* __restrict__ bq,
                unsigned short* __restrict__ outH, float* __restrict__ outHq,
                unsigned short* __restrict__ outV, float* __restrict__ outQ) {
  constexpr int K = (MODE == 1) ? 2048 : 1024;
  constexpr int N = (MODE == 1) ? 1024 : 2048;
  constexpr int BK = 32;
  constexpr int NT = K / BK;

  const int z = blockIdx.z;
  const int bm = blockIdx.x;
  const int bn = blockIdx.y;
  const int tid = threadIdx.x;
  const int lane = tid & 63;
  const int wid = tid >> 6;
  const int wr = (wid >> 1) * 64;
  const int wc = (wid & 1) * 64;
  const int l15 = lane & 15;
  const int kb = lane >> 4;

  const float* Bp = SPLITQ ? Wq : (Wmain + (size_t)z * K * N);

  __shared__ short Als[1 + SPLITQ][128][32];
  __shared__ short Bls[1 + SPLITQ][128][32];

  const f32x4 vzero = {0.f, 0.f, 0.f, 0.f};
  f32x4 acc[4][4];
#pragma unroll
  for (int m = 0; m < 4; ++m)
#pragma unroll
    for (int n = 0; n < 4; ++n) acc[m][n] = vzero;

  const int ar = tid >> 1;
  const int ak = (tid & 1) * 16;
  const int grow = bm * 128 + ar;

  const float* ApF = nullptr;
  const unsigned short* ApH = nullptr;
  if constexpr (MODE == 1) {
    const int lsel = SPLITQ ? (Lc - 1) : z;
    ApF = x + (size_t)grow * (Lc * Dc) + (size_t)lsel * Dc + ak;
  } else if constexpr (SPLITQ == 1) {
    ApF = hqF + (size_t)grow * DBc + ak;
  } else {
    ApH = hbuf + ((size_t)grow * 33 + z) * DBc + ak;
  }

  const int bnL = tid & 127;
  const int bj = tid >> 7;
  const int c0 = ((bnL >> 1) & 3) ^ bj;
  const int kc0 = c0 * 8;
  const int kc1 = (c0 ^ 2) * 8;
  const float* Bcol = Bp + (size_t)bn * 128 + bnL;

  float aF[16];
  s16x8 aH0, aH1;
  float bF[16];

  auto loadA = [&](int kt) {
    if constexpr (MODE == 2 && SPLITQ == 0) {
      const unsigned short* p = ApH + kt * BK;
      aH0 = *(const s16x8*)p;
      aH1 = *(const s16x8*)(p + 8);
    } else {
      const float* p = ApF + kt * BK;
#pragma unroll
      for (int i = 0; i < 4; ++i) {
        f32x4 t = *(const f32x4*)(p + i * 4);
#pragma unroll
        for (int j = 0; j < 4; ++j) aF[i * 4 + j] = t[j];
      }
    }
  };
  auto loadB = [&](int kt) {
    const float* p0 = Bcol + (size_t)(kt * BK + kc0) * N;
    const float* p1 = Bcol + (size_t)(kt * BK + kc1) * N;
#pragma unroll
    for (int i = 0; i < 8; ++i) bF[i] = p0[(size_t)i * N];
#pragma unroll
    for (int i = 0; i < 8; ++i) bF[8 + i] = p1[(size_t)i * N];
  };
  auto writeLDS = [&]() {
    if constexpr (MODE == 2 && SPLITQ == 0) {
      *(s16x8*)&Als[0][ar][ak] = aH0;
      *(s16x8*)&Als[0][ar][ak + 8] = aH1;
    } else if constexpr (SPLITQ == 0) {
      *(s16x8*)&Als[0][ar][ak] = pack8(aF);
      *(s16x8*)&Als[0][ar][ak + 8] = pack8(aF + 8);
    } else {
      s16x8 h0, l0, h1, l1;
      split8(aF, h0, l0);
      split8(aF + 8, h1, l1);
      *(s16x8*)&Als[0][ar][ak] = h0;
      *(s16x8*)&Als[1][ar][ak] = l0;
      *(s16x8*)&Als[0][ar][ak + 8] = h1;
      *(s16x8*)&Als[1][ar][ak + 8] = l1;
    }
    if constexpr (SPLITQ == 0) {
      *(s16x8*)&Bls[0][bnL][kc0] = pack8(bF);
      *(s16x8*)&Bls[0][bnL][kc1] = pack8(bF + 8);
    } else {
      s16x8 h0, l0, h1, l1;
      split8(bF, h0, l0);
      split8(bF + 8, h1, l1);
      *(s16x8*)&Bls[0][bnL][kc0] = h0;
      *(s16x8*)&Bls[1][bnL][kc0] = l0;
      *(s16x8*)&Bls[0][bnL][kc1] = h1;
      *(s16x8*)&Bls[1][bnL][kc1] = l1;
    }
  };

  loadA(0);
  loadB(0);
  for (int kt = 0; kt < NT; ++kt) {
    __syncthreads();
    writeLDS();
    if (kt + 1 < NT) {
      loadA(kt + 1);
      loadB(kt + 1);
    }
    __syncthreads();
    s16x8 af[4], bfv[4];
#pragma unroll
    for (int m = 0; m < 4; ++m)
      af[m] = *(const s16x8*)&Als[0][wr + m * 16 + l15][kb * 8];
#pragma unroll
    for (int n = 0; n < 4; ++n)
      bfv[n] = *(const s16x8*)&Bls[0][wc + n * 16 + l15][kb * 8];
    if constexpr (SPLITQ == 1) {
      s16x8 afl[4], bfl[4];
#pragma unroll
      for (int m = 0; m < 4; ++m)
        afl[m] = *(const s16x8*)&Als[1][wr + m * 16 + l15][kb * 8];
#pragma unroll
      for (int n = 0; n < 4; ++n)
        bfl[n] = *(const s16x8*)&Bls[1][wc + n * 16 + l15][kb * 8];
#pragma unroll
      for (int m = 0; m < 4; ++m)
#pragma unroll
        for (int n = 0; n < 4; ++n) {
          acc[m][n] = __builtin_amdgcn_mfma_f32_16x16x32_bf16(
              af[m], bfv[n], acc[m][n], 0, 0, 0);
          acc[m][n] = __builtin_amdgcn_mfma_f32_16x16x32_bf16(
              af[m], bfl[n], acc[m][n], 0, 0, 0);
          acc[m][n] = __builtin_amdgcn_mfma_f32_16x16x32_bf16(
              afl[m], bfv[n], acc[m][n], 0, 0, 0);
        }
    } else {
#pragma unroll
      for (int m = 0; m < 4; ++m)
#pragma unroll
        for (int n = 0; n < 4; ++n)
          acc[m][n] = __builtin_amdgcn_mfma_f32_16x16x32_bf16(
              af[m], bfv[n], acc[m][n], 0, 0, 0);
    }
  }

  const float* biasP = SPLITQ ? bq : (bmain + (size_t)z * N);
#pragma unroll
  for (int m = 0; m < 4; ++m) {
    const int r0 = bm * 128 + wr + m * 16 + kb * 4;
#pragma unroll
    for (int n = 0; n < 4; ++n) {
      const int col = bn * 128 + wc + n * 16 + l15;
      const float bs = biasP[col];
#pragma unroll
      for (int j = 0; j < 4; ++j) {
        const int r = r0 + j;
        const float v = acc[m][n][j] + bs;
        if constexpr (MODE == 1 && SPLITQ == 0) {
          const float g = 0.5f * v * (1.0f + erff(v * 0.70710678118f));
          outH[((size_t)r * 33 + z) * DBc + col] = (unsigned short)bf16r(g);
        } else if constexpr (MODE == 1 && SPLITQ == 1) {
          const float g = 0.5f * v * (1.0f + erff(v * 0.70710678118f));
          outHq[(size_t)r * DBc + col] = g;
        } else if constexpr (MODE == 2 && SPLITQ == 0) {
          outV[((size_t)r * 33 + z) * Dc + col] = (unsigned short)bf16r(v);
        } else {
          const float zl =
              x[(size_t)r * (Lc * Dc) + (size_t)(Lc - 1) * Dc + col];
          const float t = zl + v;
          outQ[(size_t)r * Dc + col] = (t > 0.f) ? (1.f + t) : __expf(t);
        }
      }
    }
  }
}

// ---------------------------------------------------------------------------
// Row LayerNorm over last dim W, in place on bf16 buffer. 33 slots.
// ---------------------------------------------------------------------------
template <int W>
__global__ __launch_bounds__(256)
void ln_kernel(unsigned short* __restrict__ buf, const float* __restrict__ gmain,
               const float* __restrict__ bmain) {
  constexpr int E = W / 256;
  const int z = blockIdx.x;
  const int b = blockIdx.y;
  const int tid = threadIdx.x;
  unsigned short* row = buf + ((size_t)b * 33 + z) * W;
  float v[E];
  if constexpr (E == 4) {
    s16x4 t = *(const s16x4*)(row + tid * 4);
#pragma unroll
    for (int i = 0; i < 4; ++i) v[i] = bf2f(t[i]);
  } else {
    s16x8 t = *(const s16x8*)(row + tid * 8);
#pragma unroll
    for (int i = 0; i < 8; ++i) v[i] = bf2f(t[i]);
  }
  float s = 0.f, s2 = 0.f;
#pragma unroll
  for (int i = 0; i < E; ++i) {
    s += v[i];
    s2 += v[i] * v[i];
  }
#pragma unroll
  for (int o = 32; o > 0; o >>= 1) {
    s += __shfl_xor(s, o);
    s2 += __shfl_xor(s2, o);
  }
  __shared__ float red[2][4];
  const int w = tid >> 6;
  if ((tid & 63) == 0) {
    red[0][w] = s;
    red[1][w] = s2;
  }
  __syncthreads();
  s = red[0][0] + red[0][1] + red[0][2] + red[0][3];
  s2 = red[1][0] + red[1][1] + red[1][2] + red[1][3];
  const float mu = s * (1.0f / W);
  const float var = s2 * (1.0f / W) - mu * mu;
  const float rstd = rsqrtf(var + 1e-5f);
  const float* G = gmain + (size_t)z * W;
  const float* Bt = bmain + (size_t)z * W;
  if constexpr (E == 4) {
    f32x4 gv = *(const f32x4*)(G + tid * 4);
    f32x4 bv = *(const f32x4*)(Bt + tid * 4);
    s16x4 o;
#pragma unroll
    for (int i = 0; i < 4; ++i)
      o[i] = bf16r((v[i] - mu) * rstd * gv[i] + bv[i]);
    *(s16x4*)(row + tid * 4) = o;
  } else {
    f32x4 g0 = *(const f32x4*)(G + tid * 8);
    f32x4 g1 = *(const f32x4*)(G + tid * 8 + 4);
    f32x4 b0 = *(const f32x4*)(Bt + tid * 8);
    f32x4 b1 = *(const f32x4*)(Bt + tid * 8 + 4);
    s16x8 o;
#pragma unroll
    for (int i = 0; i < 4; ++i) {
      o[i] = bf16r((v[i] - mu) * rstd * g0[i] + b0[i]);
      o[i + 4] = bf16r((v[i + 4] - mu) * rstd * g1[i] + b1[i]);
    }
    *(s16x8*)(row + tid * 8) = o;
  }
}

// ---------------------------------------------------------------------------
// f32 LayerNorm for hq (2048 rows x 1024), in place.
// ---------------------------------------------------------------------------
__global__ __launch_bounds__(256)
void ln_f32_kernel(float* __restrict__ buf, const float* __restrict__ g,
                   const float* __restrict__ bb) {
  const int r = blockIdx.x;
  const int tid = threadIdx.x;
  float* row = buf + (size_t)r * DBc;
  f32x4 v = *(const f32x4*)(row + tid * 4);
  float s = 0.f, s2 = 0.f;
#pragma unroll
  for (int i = 0; i < 4; ++i) {
    s += v[i];
    s2 += v[i] * v[i];
  }
#pragma unroll
  for (int o = 32; o > 0; o >>= 1) {
    s += __shfl_xor(s, o);
    s2 += __shfl_xor(s2, o);
  }
  __shared__ float red[2][4];
  const int w = tid >> 6;
  if ((tid & 63) == 0) {
    red[0][w] = s;
    red[1][w] = s2;
  }
  __syncthreads();
  s = red[0][0] + red[0][1] + red[0][2] + red[0][3];
  s2 = red[1][0] + red[1][1] + red[1][2] + red[1][3];
  const float mu = s * (1.0f / DBc);
  const float var = s2 * (1.0f / DBc) - mu * mu;
  const float rstd = rsqrtf(var + 1e-5f);
  f32x4 gv = *(const f32x4*)(g + tid * 4);
  f32x4 bv = *(const f32x4*)(bb + tid * 4);
  f32x4 o;
#pragma unroll
  for (int i = 0; i < 4; ++i) o[i] = (v[i] - mu) * rstd * gv[i] + bv[i];
  *(f32x4*)(row + tid * 4) = o;
}

// ---------------------------------------------------------------------------
// Final attention: per-b block. logits(33) -> softmax -> weighted values sum.
// ---------------------------------------------------------------------------
__global__ __launch_bounds__(256)
void attn_kernel(const float* __restrict__ x, const float* __restrict__ query,
                 const float* __restrict__ keys,
                 const unsigned short* __restrict__ vals,
                 float* __restrict__ out) {
  const int b = blockIdx.x;
  const int tid = threadIdx.x;
  const int d0 = tid * 8;

  float q[8];
  {
    f32x4 t0 = *(const f32x4*)(query + (size_t)b * Dc + d0);
    f32x4 t1 = *(const f32x4*)(query + (size_t)b * Dc + d0 + 4);
#pragma unroll
    for (int i = 0; i < 4; ++i) {
      q[i] = t0[i];
      q[i + 4] = t1[i];
    }
  }
  float s[33];
#pragma unroll
  for (int l = 0; l < 33; ++l) {
    const float* kp = keys + (size_t)l * Dc + d0;
    f32x4 k0 = *(const f32x4*)kp;
    f32x4 k1 = *(const f32x4*)(kp + 4);
    float t = 0.f;
#pragma unroll
    for (int i = 0; i < 4; ++i) t += q[i] * k0[i] + q[i + 4] * k1[i];
    s[l] = t;
  }
#pragma unroll
  for (int l = 0; l < 33; ++l) {
    float v = s[l];
#pragma unroll
    for (int o = 32; o > 0; o >>= 1) v += __shfl_xor(v, o);
    s[l] = v;
  }
  __shared__ float sred[4][33];
  __shared__ float sl[33];
  const int w = tid >> 6;
  if ((tid & 63) == 0) {
#pragma unroll
    for (int l = 0; l < 33; ++l) sred[w][l] = s[l];
  }
  __syncthreads();
  if (tid < 33)
    sl[tid] = sred[0][tid] + sred[1][tid] + sred[2][tid] + sred[3][tid];
  __syncthreads();

  float m = -1e30f;
#pragma unroll
  for (int l = 0; l < 33; ++l) m = fmaxf(m, sl[l]);
  float p[33];
  float sum = 0.f;
#pragma unroll
  for (int l = 0; l < 33; ++l) {
    p[l] = __expf(sl[l] - m);
    sum += p[l];
  }
  const float inv = 1.0f / sum;

  float acc8[8];
  {
    const float* zl = x + (size_t)b * (Lc * Dc) + (size_t)(Lc - 1) * Dc + d0;
    f32x4 z0 = *(const f32x4*)zl;
    f32x4 z1 = *(const f32x4*)(zl + 4);
#pragma unroll
    for (int i = 0; i < 4; ++i) {
      acc8[i] = z0[i];
      acc8[i + 4] = z1[i];
    }
  }
  const unsigned short* vb = vals + (size_t)b * 33 * Dc + d0;
#pragma unroll
  for (int l = 0; l < 33; ++l) {
    s16x8 vv = *(const s16x8*)(vb + (size_t)l * Dc);
    const float a = p[l] * inv;
#pragma unroll
    for (int i = 0; i < 8; ++i) acc8[i] += a * bf2f(vv[i]);
  }
  f32x4 o0, o1;
#pragma unroll
  for (int i = 0; i < 4; ++i) {
    o0[i] = acc8[i];
    o1[i] = acc8[i + 4];
  }
  *(f32x4*)(out + (size_t)b * Dc + d0) = o0;
  *(f32x4*)(out + (size_t)b * Dc + d0 + 4) = o1;
}

// ---------------------------------------------------------------------------
extern "C" void kernel_launch(void* const* d_in, const int* in_sizes, int n_in,
                              void* d_out, int out_size, void* d_ws,
                              size_t ws_size, hipStream_t stream) {
  const float* x = (const float*)d_in[0];
  const float* pe = (const float*)d_in[1];
  const float* Wk = (const float*)d_in[2];
  const float* W1 = (const float*)d_in[3];
  const float* b1 = (const float*)d_in[4];
  const float* ln1g = (const float*)d_in[5];
  const float* ln1b = (const float*)d_in[6];
  const float* W2 = (const float*)d_in[7];
  const float* b2 = (const float*)d_in[8];
  const float* ln2g = (const float*)d_in[9];
  const float* ln2b = (const float*)d_in[10];
  const float* Wq1 = (const float*)d_in[11];
  const float* bq1 = (const float*)d_in[12];
  const float* lnqg = (const float*)d_in[13];
  const float* lnqb = (const float*)d_in[14];
  const float* Wq2 = (const float*)d_in[15];
  const float* bq2 = (const float*)d_in[16];
  float* out = (float*)d_out;
  char* ws = (char*)d_ws;

  // ws layout (bytes):
  //   keys  f32 [33*2048]        @ 0          (270,336)
  //   query f32 [2048*2048]      @ 270336     (16,777,216)
  //   hq    f32 [2048*1024]      @ 17047552   (8,388,608)
  //   h     bf16 [2048*33*1024]  @ 25436160   (138,412,032)
  //   vals  bf16 [2048*33*2048]  @ 163848192  (276,824,064) -> end 440,672,256
  //   W1t   bf16 [33*1024*2048]  @ 163848192  (ALIAS vals: dead before GEMM2)
  //   W2t   bf16 [33*2048*1024]  @ 440672256  (138,412,032) -> end 579,084,288
  float* keysP = (float*)(ws);
  float* queryP = (float*)(ws + 270336);
  float* hqP = (float*)(ws + 17047552);
  unsigned short* hP = (unsigned short*)(ws + 25436160);
  unsigned short* valsP = (unsigned short*)(ws + 163848192);
  unsigned short* W1tP = (unsigned short*)(ws + 163848192);
  unsigned short* W2tP = (unsigned short*)(ws + 440672256);

  const bool fast = (ws_size >= 579084288ull);

  keys_kernel<<<dim3(33, 8), 256, 0, stream>>>(pe, Wk, keysP);

  gemm_fused<1, 1><<<dim3(16, 8, 1), 256, 0, stream>>>(
      x, nullptr, nullptr, nullptr, Wq1, nullptr, bq1, nullptr, hqP, nullptr,
      nullptr);

  if (fast) {
    transpose_w<2048, 1024><<<dim3(32, 16, 33), 256, 0, stream>>>(W1, W1tP);
    gemm_bf16<1><<<dim3(16, 8, 33), 256, 0, stream>>>(x, nullptr, W1tP, b1,
                                                      hP);
  } else {
    gemm_fused<1, 0><<<dim3(16, 8, 33), 256, 0, stream>>>(
        x, nullptr, nullptr, W1, nullptr, b1, nullptr, hP, nullptr, nullptr,
        nullptr);
  }

  ln_kernel<1024><<<dim3(33, 2048), 256, 0, stream>>>(hP, ln1g, ln1b);

  ln_f32_kernel<<<dim3(2048), 256, 0, stream>>>(hqP, lnqg, lnqb);

  if (fast) {
    transpose_w<1024, 2048><<<dim3(16, 32, 33), 256, 0, stream>>>(W2, W2tP);
    gemm_bf16<2><<<dim3(16, 16, 33), 256, 0, stream>>>(nullptr, hP, W2tP, b2,
                                                       valsP);
  } else {
    gemm_fused<2, 0><<<dim3(16, 16, 33), 256, 0, stream>>>(
        x, hP, nullptr, W2, nullptr, b2, nullptr, nullptr, nullptr, valsP,
        nullptr);
  }

  gemm_fused<2, 1><<<dim3(16, 16, 1), 256, 0, stream>>>(
      x, nullptr, hqP, nullptr, Wq2, nullptr, bq2, nullptr, nullptr, nullptr,
      queryP);

  ln_kernel<2048><<<dim3(33, 2048), 256, 0, stream>>>(valsP, ln2g, ln2b);

  attn_kernel<<<dim3(2048), 256, 0, stream>>>(x, queryP, keysP, valsP, out);
}

// Round 4
// 1721.629 us; speedup vs baseline: 1.3438x; 1.0238x over previous
//
#include <hip/hip_runtime.h>
#include <cstddef>
#include <cstdint>

#define Lc 33
#define Dc 2048
#define DBc 1024
#define Pc 24
#define Bc 2048

typedef __attribute__((ext_vector_type(4))) float f32x4;
typedef __attribute__((ext_vector_type(8))) short s16x8;
typedef __attribute__((ext_vector_type(4))) short s16x4;

__device__ __forceinline__ short bf16r(float f) {
  unsigned u = __float_as_uint(f);
  u = (u + 0x7fffu + ((u >> 16) & 1u)) >> 16;
  return (short)u;
}
__device__ __forceinline__ float bf2f(short s) {
  return __uint_as_float(((unsigned)(unsigned short)s) << 16);
}
__device__ __forceinline__ s16x8 pack8(const float* f) {
  s16x8 r;
#pragma unroll
  for (int i = 0; i < 8; ++i) r[i] = bf16r(f[i]);
  return r;
}
__device__ __forceinline__ void split8(const float* f, s16x8& hi, s16x8& lo) {
#pragma unroll
  for (int i = 0; i < 8; ++i) {
    short h = bf16r(f[i]);
    hi[i] = h;
    lo[i] = bf16r(f[i] - bf2f(h));
  }
}
__device__ __forceinline__ void gl_lds16(const void* g, void* l) {
  __builtin_amdgcn_global_load_lds(
      (const __attribute__((address_space(1))) unsigned int*)g,
      (__attribute__((address_space(3))) unsigned int*)l, 16, 0, 0);
}

// ---------------------------------------------------------------------------
// x f32 -> bf16 bulk convert (8 elems/thread, exact grid)
// ---------------------------------------------------------------------------
__global__ __launch_bounds__(256)
void cvt_bf16_kernel(const float* __restrict__ in,
                     unsigned short* __restrict__ outp) {
  const size_t i = ((size_t)blockIdx.x * 256 + threadIdx.x) * 8;
  f32x4 a = *(const f32x4*)(in + i);
  f32x4 b = *(const f32x4*)(in + i + 4);
  float f[8] = {a[0], a[1], a[2], a[3], b[0], b[1], b[2], b[3]};
  *(s16x8*)(outp + i) = pack8(f);
}

// ---------------------------------------------------------------------------
// keys = pos_emb @ Wk   (33 x 2048, K=24)  -- tiny, f32 exact
// ---------------------------------------------------------------------------
__global__ __launch_bounds__(256)
void keys_kernel(const float* __restrict__ pe, const float* __restrict__ Wk,
                 float* __restrict__ keys) {
  const int l = blockIdx.x;
  const int d = blockIdx.y * 256 + threadIdx.x;
  float s = 0.f;
#pragma unroll
  for (int p = 0; p < Pc; ++p) s += pe[l * Pc + p] * Wk[(size_t)p * Dc + d];
  keys[(size_t)l * Dc + d] = s;
}

// ---------------------------------------------------------------------------
// Transpose + bf16-convert weights: W [z][K][N] f32 -> Wt [z][N][K] bf16.
// ---------------------------------------------------------------------------
template <int K, int N>
__global__ __launch_bounds__(256)
void transpose_w(const float* __restrict__ W, unsigned short* __restrict__ Wt) {
  const int z = blockIdx.z;
  const int k0 = blockIdx.x * 64, n0 = blockIdx.y * 64;
  __shared__ unsigned short tile[64][66];
  const int t = threadIdx.x;
  {
    const int r = t >> 2, cq = (t & 3) * 16;
    const float* src = W + (size_t)z * K * N + (size_t)(k0 + r) * N + n0 + cq;
#pragma unroll
    for (int i = 0; i < 16; i += 4) {
      f32x4 v = *(const f32x4*)(src + i);
#pragma unroll
      for (int j = 0; j < 4; ++j)
        tile[r][cq + i + j] = (unsigned short)bf16r(v[j]);
    }
  }
  __syncthreads();
  {
    const int n = t >> 2, kc = (t & 3) * 16;
    s16x8 o0, o1;
#pragma unroll
    for (int i = 0; i < 8; ++i) {
      o0[i] = tile[kc + i][n];
      o1[i] = tile[kc + 8 + i][n];
    }
    unsigned short* dst =
        Wt + (size_t)z * N * K + (size_t)(n0 + n) * K + k0 + kc;
    *(s16x8*)dst = o0;
    *(s16x8*)(dst + 8) = o1;
  }
}

// ---------------------------------------------------------------------------
// 2-phase pipelined batched GEMM (T3-minimum): 128x128 tile, BK=64, 4 waves,
// double-buffered LDS (64 KB), global_load_lds staging of next tile issued
// BEFORE compute of current tile; drain vmcnt(0)+raw s_barrier after compute.
// A layout: [row][Lc][K] bf16 (row stride Lc*K). B: Wt [z][N][K] bf16.
// out: [row][Lc][N] bf16, optional exact-gelu epilogue.
// ---------------------------------------------------------------------------
template <int K, int N, int GELU>
__global__ __launch_bounds__(256, 2)
void gemm2ph(const unsigned short* __restrict__ A,
             const unsigned short* __restrict__ Wt,
             const float* __restrict__ bias,
             unsigned short* __restrict__ outbuf) {
  constexpr int NT = K / 64;
  const int z = blockIdx.z, bm = blockIdx.x, bn = blockIdx.y;
  const int tid = threadIdx.x, lane = tid & 63, w = tid >> 6;
  const int wr = (w >> 1) * 64, wc = (w & 1) * 64;
  const int l15 = lane & 15, kb = lane >> 4;

  __shared__ __align__(16) unsigned short Als[2][128 * 64];
  __shared__ __align__(16) unsigned short Bls[2][128 * 64];

  f32x4 acc[4][4];
#pragma unroll
  for (int m = 0; m < 4; ++m)
#pragma unroll
    for (int n = 0; n < 4; ++n) {
      acc[m][n][0] = 0.f; acc[m][n][1] = 0.f;
      acc[m][n][2] = 0.f; acc[m][n][3] = 0.f;
    }

  // gload_lds lane mapping: 64 lanes = 8 rows x 8 slots of 16B (128B row),
  // XOR-swizzled source (T2, rule #21: linear LDS dest + pre-swizzled src).
  const int rl8 = lane >> 3, sl = lane & 7;
  const int swzE = ((sl ^ rl8) << 3);

  const unsigned short* Bbase = Wt + (size_t)z * N * K;

  auto stage = [&](int buf, int kt) {
#pragma unroll
    for (int j = 0; j < 4; ++j) {
      const int rloc = w * 32 + j * 8 + rl8;
      gl_lds16(A + ((size_t)(bm * 128 + rloc) * Lc + z) * K + kt * 64 + swzE,
               (char*)&Als[buf][0] + w * 4096 + j * 1024);
      gl_lds16(Bbase + (size_t)(bn * 128 + rloc) * K + kt * 64 + swzE,
               (char*)&Bls[buf][0] + w * 4096 + j * 1024);
    }
  };

  stage(0, 0);
  asm volatile("s_waitcnt vmcnt(0)" ::: "memory");
  __builtin_amdgcn_s_barrier();

  for (int kt = 0; kt < NT; ++kt) {
    const int cur = kt & 1;
    if (kt + 1 < NT) stage(cur ^ 1, kt + 1);
    // ---- compute from buf[cur] ----
#pragma unroll
    for (int kk = 0; kk < 2; ++kk) {
      s16x8 af[4], bfv[4];
#pragma unroll
      for (int m = 0; m < 4; ++m) {
        const int row = wr + m * 16 + l15;
        const int slot = kk * 4 + kb;
        af[m] = *(const s16x8*)((const char*)&Als[cur][0] + row * 128 +
                                ((slot ^ (row & 7)) << 4));
      }
#pragma unroll
      for (int n = 0; n < 4; ++n) {
        const int row = wc + n * 16 + l15;
        const int slot = kk * 4 + kb;
        bfv[n] = *(const s16x8*)((const char*)&Bls[cur][0] + row * 128 +
                                 ((slot ^ (row & 7)) << 4));
      }
#pragma unroll
      for (int m = 0; m < 4; ++m)
#pragma unroll
        for (int n = 0; n < 4; ++n)
          acc[m][n] = __builtin_amdgcn_mfma_f32_16x16x32_bf16(
              af[m], bfv[n], acc[m][n], 0, 0, 0);
    }
    asm volatile("s_waitcnt vmcnt(0)" ::: "memory");
    __builtin_amdgcn_s_barrier();
  }

  const float* biasP = bias + (size_t)z * N;
#pragma unroll
  for (int m = 0; m < 4; ++m) {
    const int r0 = bm * 128 + wr + m * 16 + kb * 4;
#pragma unroll
    for (int n = 0; n < 4; ++n) {
      const int col = bn * 128 + wc + n * 16 + l15;
      const float bs = biasP[col];
#pragma unroll
      for (int j = 0; j < 4; ++j) {
        const int r = r0 + j;
        float v = acc[m][n][j] + bs;
        if constexpr (GELU) v = 0.5f * v * (1.0f + erff(v * 0.70710678118f));
        outbuf[((size_t)r * Lc + z) * N + col] = (unsigned short)bf16r(v);
      }
    }
  }
}

// ---------------------------------------------------------------------------
// Old-style fused GEMM (reg-staged, unswizzled). Used for the split-precision
// query path (SPLITQ=1) and as main-path fallback if ws is too small.
// ---------------------------------------------------------------------------
template <int MODE, int SPLITQ>
__global__ __launch_bounds__(256, 2)
void gemm_fused(const float* __restrict__ x,
                const unsigned short* __restrict__ hbuf,
                const float* __restrict__ hqF,
                const float* __restrict__ Wmain, const float* __restrict__ Wq,
                const float* __restrict__ bmain, const float* __restrict__ bq,
                unsigned short* __restrict__ outH, float* __restrict__ outHq,
                unsigned short* __restrict__ outV, float* __restrict__ outQ) {
  constexpr int K = (MODE == 1) ? 2048 : 1024;
  constexpr int N = (MODE == 1) ? 1024 : 2048;
  constexpr int BK = 32;
  constexpr int NT = K / BK;

  const int z = blockIdx.z;
  const int bm = blockIdx.x;
  const int bn = blockIdx.y;
  const int tid = threadIdx.x;
  const int lane = tid & 63;
  const int wid = tid >> 6;
  const int wr = (wid >> 1) * 64;
  const int wc = (wid & 1) * 64;
  const int l15 = lane & 15;
  const int kb = lane >> 4;

  const float* Bp = SPLITQ ? Wq : (Wmain + (size_t)z * K * N);

  __shared__ short Als[1 + SPLITQ][128][32];
  __shared__ short Bls[1 + SPLITQ][128][32];

  const f32x4 vzero = {0.f, 0.f, 0.f, 0.f};
  f32x4 acc[4][4];
#pragma unroll
  for (int m = 0; m < 4; ++m)
#pragma unroll
    for (int n = 0; n < 4; ++n) acc[m][n] = vzero;

  const int ar = tid >> 1;
  const int ak = (tid & 1) * 16;
  const int grow = bm * 128 + ar;

  const float* ApF = nullptr;
  const unsigned short* ApH = nullptr;
  if constexpr (MODE == 1) {
    const int lsel = SPLITQ ? (Lc - 1) : z;
    ApF = x + (size_t)grow * (Lc * Dc) + (size_t)lsel * Dc + ak;
  } else if constexpr (SPLITQ == 1) {
    ApF = hqF + (size_t)grow * DBc + ak;
  } else {
    ApH = hbuf + ((size_t)grow * 33 + z) * DBc + ak;
  }

  const int bnL = tid & 127;
  const int bj = tid >> 7;
  const int c0 = ((bnL >> 1) & 3) ^ bj;
  const int kc0 = c0 * 8;
  const int kc1 = (c0 ^ 2) * 8;
  const float* Bcol = Bp + (size_t)bn * 128 + bnL;

  float aF[16];
  s16x8 aH0, aH1;
  float bF[16];

  auto loadA = [&](int kt) {
    if constexpr (MODE == 2 && SPLITQ == 0) {
      const unsigned short* p = ApH + kt * BK;
      aH0 = *(const s16x8*)p;
      aH1 = *(const s16x8*)(p + 8);
    } else {
      const float* p = ApF + kt * BK;
#pragma unroll
      for (int i = 0; i < 4; ++i) {
        f32x4 t = *(const f32x4*)(p + i * 4);
#pragma unroll
        for (int j = 0; j < 4; ++j) aF[i * 4 + j] = t[j];
      }
    }
  };
  auto loadB = [&](int kt) {
    const float* p0 = Bcol + (size_t)(kt * BK + kc0) * N;
    const float* p1 = Bcol + (size_t)(kt * BK + kc1) * N;
#pragma unroll
    for (int i = 0; i < 8; ++i) bF[i] = p0[(size_t)i * N];
#pragma unroll
    for (int i = 0; i < 8; ++i) bF[8 + i] = p1[(size_t)i * N];
  };
  auto writeLDS = [&]() {
    if constexpr (MODE == 2 && SPLITQ == 0) {
      *(s16x8*)&Als[0][ar][ak] = aH0;
      *(s16x8*)&Als[0][ar][ak + 8] = aH1;
    } else if constexpr (SPLITQ == 0) {
      *(s16x8*)&Als[0][ar][ak] = pack8(aF);
      *(s16x8*)&Als[0][ar][ak + 8] = pack8(aF + 8);
    } else {
      s16x8 h0, l0, h1, l1;
      split8(aF, h0, l0);
      split8(aF + 8, h1, l1);
      *(s16x8*)&Als[0][ar][ak] = h0;
      *(s16x8*)&Als[1][ar][ak] = l0;
      *(s16x8*)&Als[0][ar][ak + 8] = h1;
      *(s16x8*)&Als[1][ar][ak + 8] = l1;
    }
    if constexpr (SPLITQ == 0) {
      *(s16x8*)&Bls[0][bnL][kc0] = pack8(bF);
      *(s16x8*)&Bls[0][bnL][kc1] = pack8(bF + 8);
    } else {
      s16x8 h0, l0, h1, l1;
      split8(bF, h0, l0);
      split8(bF + 8, h1, l1);
      *(s16x8*)&Bls[0][bnL][kc0] = h0;
      *(s16x8*)&Bls[1][bnL][kc0] = l0;
      *(s16x8*)&Bls[0][bnL][kc1] = h1;
      *(s16x8*)&Bls[1][bnL][kc1] = l1;
    }
  };

  loadA(0);
  loadB(0);
  for (int kt = 0; kt < NT; ++kt) {
    __syncthreads();
    writeLDS();
    if (kt + 1 < NT) {
      loadA(kt + 1);
      loadB(kt + 1);
    }
    __syncthreads();
    s16x8 af[4], bfv[4];
#pragma unroll
    for (int m = 0; m < 4; ++m)
      af[m] = *(const s16x8*)&Als[0][wr + m * 16 + l15][kb * 8];
#pragma unroll
    for (int n = 0; n < 4; ++n)
      bfv[n] = *(const s16x8*)&Bls[0][wc + n * 16 + l15][kb * 8];
    if constexpr (SPLITQ == 1) {
      s16x8 afl[4], bfl[4];
#pragma unroll
      for (int m = 0; m < 4; ++m)
        afl[m] = *(const s16x8*)&Als[1][wr + m * 16 + l15][kb * 8];
#pragma unroll
      for (int n = 0; n < 4; ++n)
        bfl[n] = *(const s16x8*)&Bls[1][wc + n * 16 + l15][kb * 8];
#pragma unroll
      for (int m = 0; m < 4; ++m)
#pragma unroll
        for (int n = 0; n < 4; ++n) {
          acc[m][n] = __builtin_amdgcn_mfma_f32_16x16x32_bf16(
              af[m], bfv[n], acc[m][n], 0, 0, 0);
          acc[m][n] = __builtin_amdgcn_mfma_f32_16x16x32_bf16(
              af[m], bfl[n], acc[m][n], 0, 0, 0);
          acc[m][n] = __builtin_amdgcn_mfma_f32_16x16x32_bf16(
              afl[m], bfv[n], acc[m][n], 0, 0, 0);
        }
    } else {
#pragma unroll
      for (int m = 0; m < 4; ++m)
#pragma unroll
        for (int n = 0; n < 4; ++n)
          acc[m][n] = __builtin_amdgcn_mfma_f32_16x16x32_bf16(
              af[m], bfv[n], acc[m][n], 0, 0, 0);
    }
  }

  const float* biasP = SPLITQ ? bq : (bmain + (size_t)z * N);
#pragma unroll
  for (int m = 0; m < 4; ++m) {
    const int r0 = bm * 128 + wr + m * 16 + kb * 4;
#pragma unroll
    for (int n = 0; n < 4; ++n) {
      const int col = bn * 128 + wc + n * 16 + l15;
      const float bs = biasP[col];
#pragma unroll
      for (int j = 0; j < 4; ++j) {
        const int r = r0 + j;
        const float v = acc[m][n][j] + bs;
        if constexpr (MODE == 1 && SPLITQ == 0) {
          const float g = 0.5f * v * (1.0f + erff(v * 0.70710678118f));
          outH[((size_t)r * 33 + z) * DBc + col] = (unsigned short)bf16r(g);
        } else if constexpr (MODE == 1 && SPLITQ == 1) {
          const float g = 0.5f * v * (1.0f + erff(v * 0.70710678118f));
          outHq[(size_t)r * DBc + col] = g;
        } else if constexpr (MODE == 2 && SPLITQ == 0) {
          outV[((size_t)r * 33 + z) * Dc + col] = (unsigned short)bf16r(v);
        } else {
          const float zl =
              x[(size_t)r * (Lc * Dc) + (size_t)(Lc - 1) * Dc + col];
          const float t = zl + v;
          outQ[(size_t)r * Dc + col] = (t > 0.f) ? (1.f + t) : __expf(t);
        }
      }
    }
  }
}

// ---------------------------------------------------------------------------
// Row LayerNorm over last dim W, in place on bf16 buffer. 33 slots.
// ---------------------------------------------------------------------------
template <int W>
__global__ __launch_bounds__(256)
void ln_kernel(unsigned short* __restrict__ buf, const float* __restrict__ gmain,
               const float* __restrict__ bmain) {
  constexpr int E = W / 256;
  const int z = blockIdx.x;
  const int b = blockIdx.y;
  const int tid = threadIdx.x;
  unsigned short* row = buf + ((size_t)b * 33 + z) * W;
  float v[E];
  if constexpr (E == 4) {
    s16x4 t = *(const s16x4*)(row + tid * 4);
#pragma unroll
    for (int i = 0; i < 4; ++i) v[i] = bf2f(t[i]);
  } else {
    s16x8 t = *(const s16x8*)(row + tid * 8);
#pragma unroll
    for (int i = 0; i < 8; ++i) v[i] = bf2f(t[i]);
  }
  float s = 0.f, s2 = 0.f;
#pragma unroll
  for (int i = 0; i < E; ++i) {
    s += v[i];
    s2 += v[i] * v[i];
  }
#pragma unroll
  for (int o = 32; o > 0; o >>= 1) {
    s += __shfl_xor(s, o);
    s2 += __shfl_xor(s2, o);
  }
  __shared__ float red[2][4];
  const int w = tid >> 6;
  if ((tid & 63) == 0) {
    red[0][w] = s;
    red[1][w] = s2;
  }
  __syncthreads();
  s = red[0][0] + red[0][1] + red[0][2] + red[0][3];
  s2 = red[1][0] + red[1][1] + red[1][2] + red[1][3];
  const float mu = s * (1.0f / W);
  const float var = s2 * (1.0f / W) - mu * mu;
  const float rstd = rsqrtf(var + 1e-5f);
  const float* G = gmain + (size_t)z * W;
  const float* Bt = bmain + (size_t)z * W;
  if constexpr (E == 4) {
    f32x4 gv = *(const f32x4*)(G + tid * 4);
    f32x4 bv = *(const f32x4*)(Bt + tid * 4);
    s16x4 o;
#pragma unroll
    for (int i = 0; i < 4; ++i)
      o[i] = bf16r((v[i] - mu) * rstd * gv[i] + bv[i]);
    *(s16x4*)(row + tid * 4) = o;
  } else {
    f32x4 g0 = *(const f32x4*)(G + tid * 8);
    f32x4 g1 = *(const f32x4*)(G + tid * 8 + 4);
    f32x4 b0 = *(const f32x4*)(Bt + tid * 8);
    f32x4 b1 = *(const f32x4*)(Bt + tid * 8 + 4);
    s16x8 o;
#pragma unroll
    for (int i = 0; i < 4; ++i) {
      o[i] = bf16r((v[i] - mu) * rstd * g0[i] + b0[i]);
      o[i + 4] = bf16r((v[i + 4] - mu) * rstd * g1[i] + b1[i]);
    }
    *(s16x8*)(row + tid * 8) = o;
  }
}

// ---------------------------------------------------------------------------
// f32 LayerNorm for hq (2048 rows x 1024), in place.
// ---------------------------------------------------------------------------
__global__ __launch_bounds__(256)
void ln_f32_kernel(float* __restrict__ buf, const float* __restrict__ g,
                   const float* __restrict__ bb) {
  const int r = blockIdx.x;
  const int tid = threadIdx.x;
  float* row = buf + (size_t)r * DBc;
  f32x4 v = *(const f32x4*)(row + tid * 4);
  float s = 0.f, s2 = 0.f;
#pragma unroll
  for (int i = 0; i < 4; ++i) {
    s += v[i];
    s2 += v[i] * v[i];
  }
#pragma unroll
  for (int o = 32; o > 0; o >>= 1) {
    s += __shfl_xor(s, o);
    s2 += __shfl_xor(s2, o);
  }
  __shared__ float red[2][4];
  const int w = tid >> 6;
  if ((tid & 63) == 0) {
    red[0][w] = s;
    red[1][w] = s2;
  }
  __syncthreads();
  s = red[0][0] + red[0][1] + red[0][2] + red[0][3];
  s2 = red[1][0] + red[1][1] + red[1][2] + red[1][3];
  const float mu = s * (1.0f / DBc);
  const float var = s2 * (1.0f / DBc) - mu * mu;
  const float rstd = rsqrtf(var + 1e-5f);
  f32x4 gv = *(const f32x4*)(g + tid * 4);
  f32x4 bv = *(const f32x4*)(bb + tid * 4);
  f32x4 o;
#pragma unroll
  for (int i = 0; i < 4; ++i) o[i] = (v[i] - mu) * rstd * gv[i] + bv[i];
  *(f32x4*)(row + tid * 4) = o;
}

// ---------------------------------------------------------------------------
// Final attention: per-b block. logits(33) -> softmax -> weighted values sum.
// ---------------------------------------------------------------------------
__global__ __launch_bounds__(256)
void attn_kernel(const float* __restrict__ x, const float* __restrict__ query,
                 const float* __restrict__ keys,
                 const unsigned short* __restrict__ vals,
                 float* __restrict__ out) {
  const int b = blockIdx.x;
  const int tid = threadIdx.x;
  const int d0 = tid * 8;

  float q[8];
  {
    f32x4 t0 = *(const f32x4*)(query + (size_t)b * Dc + d0);
    f32x4 t1 = *(const f32x4*)(query + (size_t)b * Dc + d0 + 4);
#pragma unroll
    for (int i = 0; i < 4; ++i) {
      q[i] = t0[i];
      q[i + 4] = t1[i];
    }
  }
  float s[33];
#pragma unroll
  for (int l = 0; l < 33; ++l) {
    const float* kp = keys + (size_t)l * Dc + d0;
    f32x4 k0 = *(const f32x4*)kp;
    f32x4 k1 = *(const f32x4*)(kp + 4);
    float t = 0.f;
#pragma unroll
    for (int i = 0; i < 4; ++i) t += q[i] * k0[i] + q[i + 4] * k1[i];
    s[l] = t;
  }
#pragma unroll
  for (int l = 0; l < 33; ++l) {
    float v = s[l];
#pragma unroll
    for (int o = 32; o > 0; o >>= 1) v += __shfl_xor(v, o);
    s[l] = v;
  }
  __shared__ float sred[4][33];
  __shared__ float sl[33];
  const int w = tid >> 6;
  if ((tid & 63) == 0) {
#pragma unroll
    for (int l = 0; l < 33; ++l) sred[w][l] = s[l];
  }
  __syncthreads();
  if (tid < 33)
    sl[tid] = sred[0][tid] + sred[1][tid] + sred[2][tid] + sred[3][tid];
  __syncthreads();

  float m = -1e30f;
#pragma unroll
  for (int l = 0; l < 33; ++l) m = fmaxf(m, sl[l]);
  float p[33];
  float sum = 0.f;
#pragma unroll
  for (int l = 0; l < 33; ++l) {
    p[l] = __expf(sl[l] - m);
    sum += p[l];
  }
  const float inv = 1.0f / sum;

  float acc8[8];
  {
    const float* zl = x + (size_t)b * (Lc * Dc) + (size_t)(Lc - 1) * Dc + d0;
    f32x4 z0 = *(const f32x4*)zl;
    f32x4 z1 = *(const f32x4*)(zl + 4);
#pragma unroll
    for (int i = 0; i < 4; ++i) {
      acc8[i] = z0[i];
      acc8[i + 4] = z1[i];
    }
  }
  const unsigned short* vb = vals + (size_t)b * 33 * Dc + d0;
#pragma unroll
  for (int l = 0; l < 33; ++l) {
    s16x8 vv = *(const s16x8*)(vb + (size_t)l * Dc);
    const float a = p[l] * inv;
#pragma unroll
    for (int i = 0; i < 8; ++i) acc8[i] += a * bf2f(vv[i]);
  }
  f32x4 o0, o1;
#pragma unroll
  for (int i = 0; i < 4; ++i) {
    o0[i] = acc8[i];
    o1[i] = acc8[i + 4];
  }
  *(f32x4*)(out + (size_t)b * Dc + d0) = o0;
  *(f32x4*)(out + (size_t)b * Dc + d0 + 4) = o1;
}

// ---------------------------------------------------------------------------
extern "C" void kernel_launch(void* const* d_in, const int* in_sizes, int n_in,
                              void* d_out, int out_size, void* d_ws,
                              size_t ws_size, hipStream_t stream) {
  const float* x = (const float*)d_in[0];
  const float* pe = (const float*)d_in[1];
  const float* Wk = (const float*)d_in[2];
  const float* W1 = (const float*)d_in[3];
  const float* b1 = (const float*)d_in[4];
  const float* ln1g = (const float*)d_in[5];
  const float* ln1b = (const float*)d_in[6];
  const float* W2 = (const float*)d_in[7];
  const float* b2 = (const float*)d_in[8];
  const float* ln2g = (const float*)d_in[9];
  const float* ln2b = (const float*)d_in[10];
  const float* Wq1 = (const float*)d_in[11];
  const float* bq1 = (const float*)d_in[12];
  const float* lnqg = (const float*)d_in[13];
  const float* lnqb = (const float*)d_in[14];
  const float* Wq2 = (const float*)d_in[15];
  const float* bq2 = (const float*)d_in[16];
  float* out = (float*)d_out;
  char* ws = (char*)d_ws;

  // ws layout (bytes), lifetime-aliased:
  //   keys  f32 [33*2048]        @ 0          (270,336)           whole call
  //   query f32 [2048*2048]      @ 270336     (16,777,216)        gemm2q->attn
  //   hq    f32 [2048*1024]      @ 17047552   (8,388,608)         mid
  //   h     bf16 [2048*33*1024]  @ 25436160   (138,412,032)       g1->g2
  //   xbf   bf16 [2048*33*2048]  @ 163848192  (276,824,064)       cvt->g1
  //   vals  bf16 [2048*33*2048]  @ 163848192  (ALIAS xbf: g2->attn)
  //   W1t   bf16 [33*1024*2048]  @ 440672256  (138,412,032)       t1->g1
  //   W2t   bf16 [33*2048*1024]  @ 440672256  (ALIAS W1t: t2->g2)
  float* keysP = (float*)(ws);
  float* queryP = (float*)(ws + 270336);
  float* hqP = (float*)(ws + 17047552);
  unsigned short* hP = (unsigned short*)(ws + 25436160);
  unsigned short* xbfP = (unsigned short*)(ws + 163848192);
  unsigned short* valsP = (unsigned short*)(ws + 163848192);
  unsigned short* W1tP = (unsigned short*)(ws + 440672256);
  unsigned short* W2tP = (unsigned short*)(ws + 440672256);

  const bool fast = (ws_size >= 579084288ull);

  keys_kernel<<<dim3(33, 8), 256, 0, stream>>>(pe, Wk, keysP);

  gemm_fused<1, 1><<<dim3(16, 8, 1), 256, 0, stream>>>(
      x, nullptr, nullptr, nullptr, Wq1, nullptr, bq1, nullptr, hqP, nullptr,
      nullptr);

  if (fast) {
    // x -> bf16 (138.4M elems / 8 per thread / 256 per block = 67584 blocks)
    cvt_bf16_kernel<<<dim3(67584), 256, 0, stream>>>(x, xbfP);
    transpose_w<2048, 1024><<<dim3(32, 16, 33), 256, 0, stream>>>(W1, W1tP);
    gemm2ph<2048, 1024, 1><<<dim3(16, 8, 33), 256, 0, stream>>>(xbfP, W1tP,
                                                                b1, hP);
  } else {
    gemm_fused<1, 0><<<dim3(16, 8, 33), 256, 0, stream>>>(
        x, nullptr, nullptr, W1, nullptr, b1, nullptr, hP, nullptr, nullptr,
        nullptr);
  }

  ln_kernel<1024><<<dim3(33, 2048), 256, 0, stream>>>(hP, ln1g, ln1b);

  ln_f32_kernel<<<dim3(2048), 256, 0, stream>>>(hqP, lnqg, lnqb);

  if (fast) {
    // W2t overwrites W1t slot (dead after GEMM1); vals overwrite xbf (dead).
    transpose_w<1024, 2048><<<dim3(16, 32, 33), 256, 0, stream>>>(W2, W2tP);
    gemm2ph<1024, 2048, 0><<<dim3(16, 16, 33), 256, 0, stream>>>(hP, W2tP, b2,
                                                                 valsP);
  } else {
    gemm_fused<2, 0><<<dim3(16, 16, 33), 256, 0, stream>>>(
        x, hP, nullptr, W2, nullptr, b2, nullptr, nullptr, nullptr, valsP,
        nullptr);
  }

  gemm_fused<2, 1><<<dim3(16, 16, 1), 256, 0, stream>>>(
      x, nullptr, hqP, nullptr, Wq2, nullptr, bq2, nullptr, nullptr, nullptr,
      queryP);

  ln_kernel<2048><<<dim3(33, 2048), 256, 0, stream>>>(valsP, ln2g, ln2b);

  attn_kernel<<<dim3(2048), 256, 0, stream>>>(x, queryP, keysP, valsP, out);
}